// Round 7
// baseline (291.376 us; speedup 1.0000x reference)
//
#include <hip/hip_runtime.h>

// B=2, T=8, H=16, W=16, E=512, n=16, d=32, S=4096, WINDOW=4
// frames BT=16, per-frame L2=512, keys/frame-window = 2048

#define LOG2T_OVER_16 0.83048202372184059f   // log2(10000)/16
#define SCL 0.25505837391169026f             // (1/sqrt(32)) * log2(e)

typedef unsigned short u16;
typedef unsigned int u32;
typedef __attribute__((ext_vector_type(2))) unsigned int u32x2;
typedef __attribute__((ext_vector_type(4))) float f32x4;
typedef __attribute__((ext_vector_type(8))) short s16x8;

__device__ __forceinline__ u16 bf16b(float x) {
  u32 u = __float_as_uint(x);
  u32 r = u + 0x7FFFu + ((u >> 16) & 1u);   // RNE
  return (u16)(r >> 16);
}
__device__ __forceinline__ float bf2f(u16 s) {
  return __uint_as_float(((u32)s) << 16);
}
__device__ __forceinline__ u32 cvtpk(float lo, float hi) {
  u32 r;
  asm("v_cvt_pk_bf16_f32 %0, %1, %2" : "=v"(r) : "v"(lo), "v"(hi));
  return r;
}

__device__ __forceinline__ void gld_lds16(const u16* g, u16* l) {
  __builtin_amdgcn_global_load_lds(
      (const __attribute__((address_space(1))) unsigned int*)g,
      (__attribute__((address_space(3))) unsigned int*)l, 16, 0, 0);
}

// ---------------- fused cast f32 -> bf16 of hs, w_in, w_out (contiguous dst) ----------------
__global__ __launch_bounds__(256) void cast3_bf16(
    const float* __restrict__ a, const float* __restrict__ b,
    const float* __restrict__ c, u16* __restrict__ dst) {
  const int i = blockIdx.x * 256 + threadIdx.x;
  const float* s;
  int so;
  if (i < 524288) { s = a; so = i; }
  else if (i < 622592) { s = b; so = i - 524288; }
  else { s = c; so = i - 622592; }
  float4 x = ((const float4*)s)[so * 2], y = ((const float4*)s)[so * 2 + 1];
  union { u32 u[4]; s16x8 v; } w;
  w.u[0] = cvtpk(x.x, x.y); w.u[1] = cvtpk(x.z, x.w);
  w.u[2] = cvtpk(y.x, y.y); w.u[3] = cvtpk(y.z, y.w);
  ((s16x8*)dst)[i] = w.v;
}

// ---------------- MFMA GEMM core ----------------
// MODE 0: bf16 C row-major. MODE 1: f32 C row-major. MODE 2: bf16 written
// transposed into vt[((frame*16+h)*32+dd)*512 + key] (frame=row>>9, key=row&511).
template<int MODE>
__device__ __forceinline__ void gemm_core(
    const u16* __restrict__ A, const u16* __restrict__ Bw,
    const float* __restrict__ bias, void* __restrict__ Cp,
    int N, int K, int lda, float scale, u16* As, u16* Bs) {
  const int tid = threadIdx.x;
  const int row0 = blockIdx.y * 128;
  const int col0 = blockIdx.x * 128;
  const int lane = tid & 63, wid = tid >> 6;
  const int col = lane & 15, g = lane >> 4;
  const int wm = wid >> 1, wn = wid & 1;

  const int s0 = tid, s1 = 256 + tid;
  const int r0 = s0 >> 2, kp0 = (s0 & 3) * 8;
  const int r1 = s1 >> 2, kp1 = (s1 & 3) * 8;

  f32x4 acc[4][4] = {};

  auto stage = [&](int buf, int k0) {
    u16* ab = As + buf * 4096;
    u16* bb = Bs + buf * 4096;
    gld_lds16(A + (size_t)(row0 + r0) * lda + k0 + kp0, ab + s0 * 8);
    gld_lds16(A + (size_t)(row0 + r1) * lda + k0 + kp1, ab + s1 * 8);
    gld_lds16(Bw + (size_t)(col0 + r0) * K + k0 + kp0, bb + s0 * 8);
    gld_lds16(Bw + (size_t)(col0 + r1) * K + k0 + kp1, bb + s1 * 8);
  };

  stage(0, 0);
  asm volatile("s_waitcnt vmcnt(0)" ::: "memory");
  __syncthreads();

  const int NT = K / 32;
  int cur = 0;
  for (int t = 0; t < NT; ++t) {
    if (t + 1 < NT) stage(cur ^ 1, (t + 1) * 32);
    const u16* ab = As + cur * 4096;
    const u16* bb = Bs + cur * 4096;
    s16x8 a[4], b[4];
    #pragma unroll
    for (int i = 0; i < 4; ++i)
      a[i] = *(const s16x8*)(ab + (wm * 64 + i * 16 + col) * 32 + g * 8);
    #pragma unroll
    for (int i = 0; i < 4; ++i)
      b[i] = *(const s16x8*)(bb + (wn * 64 + i * 16 + col) * 32 + g * 8);
    #pragma unroll
    for (int mi = 0; mi < 4; ++mi)
      #pragma unroll
      for (int ni = 0; ni < 4; ++ni)
        acc[mi][ni] = __builtin_amdgcn_mfma_f32_16x16x32_bf16(a[mi], b[ni], acc[mi][ni], 0, 0, 0);
    asm volatile("s_waitcnt vmcnt(0)" ::: "memory");
    __syncthreads();
    cur ^= 1;
  }

  const int crow = row0 + wm * 64, ccol = col0 + wn * 64;
  #pragma unroll
  for (int mi = 0; mi < 4; ++mi) {
    #pragma unroll
    for (int ni = 0; ni < 4; ++ni) {
      const int cc = ccol + ni * 16 + col;
      const float bb_ = bias ? bias[cc] : 0.0f;
      if (MODE == 2) {
        const int key0 = crow + mi * 16 + g * 4;   // 4 consecutive keys
        u16* dst = (u16*)Cp +
            ((size_t)((key0 >> 9) * 16 + (cc >> 5)) * 32 + (cc & 31)) * 512 + (key0 & 511);
        union { u16 s[4]; u32x2 v; } pk;
        #pragma unroll
        for (int r = 0; r < 4; ++r) pk.s[r] = bf16b(acc[mi][ni][r] + bb_);
        *(u32x2*)dst = pk.v;
      } else {
        #pragma unroll
        for (int r = 0; r < 4; ++r) {
          const int rr = crow + mi * 16 + g * 4 + r;
          float v = (acc[mi][ni][r] + bb_) * scale;
          if (MODE == 1) ((float*)Cp)[(size_t)rr * N + cc] = v;
          else           ((u16*)Cp)[(size_t)rr * N + cc] = bf16b(v);
        }
      }
    }
  }
}

__global__ __launch_bounds__(256) void gemm_bf16(
    const u16* __restrict__ A, const u16* __restrict__ Bw,
    const float* __restrict__ bias, u16* __restrict__ C, int N, int K, float scale) {
  __shared__ u16 As[2 * 4096];
  __shared__ u16 Bs[2 * 4096];
  gemm_core<0>(A, Bw, bias, C, N, K, K, scale, As, Bs);
}

__global__ __launch_bounds__(256) void gemm_f32out(
    const u16* __restrict__ A, const u16* __restrict__ Bw,
    const float* __restrict__ bias, float* __restrict__ C, int N, int K, float scale) {
  __shared__ u16 As[2 * 4096];
  __shared__ u16 Bs[2 * 4096];
  gemm_core<1>(A, Bw, bias, C, N, K, K, scale, As, Bs);
}

// batched second projection: z=0 qh(+bq,*SCL) | z=1 kbf(raw) | z=2 V: reads qkv
// strided (lda=1536), writes vt transposed (+bv). Cb must NOT alias qkv.
__global__ __launch_bounds__(256) void gemm2_batched(
    const u16* __restrict__ Ab, const u16* __restrict__ qkv,
    const u16* __restrict__ Wb, const float* __restrict__ b_in,
    u16* __restrict__ Cb) {
  __shared__ u16 As[2 * 4096];
  __shared__ u16 Bs[2 * 4096];
  const int z = blockIdx.z;
  const u16* Bw = Wb + (size_t)z * 262144;
  u16* C = Cb + (size_t)z * 4194304;
  if (z == 2) {
    gemm_core<2>(qkv + 1024, Bw, b_in + 1024, C, 512, 512, 1536, 1.0f, As, Bs);
  } else {
    const float* bias = (z == 0) ? b_in : nullptr;
    const float scale = (z == 0) ? SCL : 1.0f;
    gemm_core<0>(Ab + (size_t)z * 4194304, Bw, bias, C, 512, 512, 512, scale, As, Bs);
  }
}

// ------------- angle table: tab[j][u] = {cos, sin} (512 x 16) -------------
__global__ __launch_bounds__(256) void ang_table_kernel(float2* __restrict__ tab) {
  const int idx = blockIdx.x * 256 + threadIdx.x;  // 0..8191
  const int j = idx >> 4, u = idx & 15;
  float ang;
  if (j < 256) {
    ang = (float)j * exp2f(-(float)u * LOG2T_OVER_16);
  } else {
    const int jj = j - 256, hh = jj >> 4, ww = jj & 15;
    ang = (u < 8) ? (float)hh * exp2f(-(float)(2 * u) * LOG2T_OVER_16)
                  : (float)ww * exp2f(-(float)(2 * (u - 8) + 1) * LOG2T_OVER_16);
  }
  float s, c;
  sincosf(ang, &s, &c);
  tab[idx] = make_float2(c, s);
}

// ------------- RoPE + relayout (bf16): qkv(8192x1536) -> qm/kc (8192x512) -------------
__global__ __launch_bounds__(256) void rope_relayout_bf(
    const u16* __restrict__ qkv, const float2* __restrict__ tab,
    u16* __restrict__ qm, u16* __restrict__ kc) {
  const int R = blockIdx.x * 2 + (threadIdx.x >> 7);   // row 0..8191
  const int t2 = threadIdx.x & 127;
  const int j = R & 511, bt = R >> 9;
  const int b = bt >> 3, tt = bt & 7;
  const int head = t2 >> 3, u0 = (t2 & 7) * 2;
  const int e0 = head * 32 + u0 * 2;

  const int tok = (j < 256) ? (b * 4096 + tt * 256 + j)
                            : (b * 4096 + 2048 + tt * 256 + (j - 256));
  float4 cs = *(const float4*)&tab[j * 16 + u0];
  const float c0 = cs.x, s0 = cs.y, c1 = cs.z, s1 = cs.w;

  const size_t base = (size_t)tok * 1536 + e0;
  const size_t orow = (size_t)R * 512 + e0;

  auto rot = [&](u32x2 in) -> u32x2 {
    float r0 = bf2f((u16)(in[0] & 0xffff)), i0 = bf2f((u16)(in[0] >> 16));
    float r1 = bf2f((u16)(in[1] & 0xffff)), i1 = bf2f((u16)(in[1] >> 16));
    u32x2 o;
    o[0] = cvtpk(r0 * c0 - i0 * s0, r0 * s0 + i0 * c0);
    o[1] = cvtpk(r1 * c1 - i1 * s1, r1 * s1 + i1 * c1);
    return o;
  };
  *(u32x2*)(qm + orow) = rot(*(const u32x2*)(qkv + base));
  *(u32x2*)(kc + orow) = rot(*(const u32x2*)(qkv + base + 512));
}

// ------------- tep[i][c] = te[i] @ Wk[c,:] + bk[c]  (4 x 512, exact f32) -------------
__global__ __launch_bounds__(256) void tep_kernel(
    const float* __restrict__ te, const float* __restrict__ Wk,
    const float* __restrict__ bk, float* __restrict__ tep) {
  const int idx = blockIdx.x * 256 + threadIdx.x;
  const int i = idx >> 9, c = idx & 511;
  float s = bk[c];
  const float* terow = te + i * 512;
  const float* wrow = Wk + (size_t)c * 512;
  #pragma unroll 8
  for (int e = 0; e < 512; ++e) s = fmaf(terow[e], wrow[e], s);
  tep[idx] = s;
}

// ------------- MFMA flash attention: 8 waves/block = (4 slots) x (2 row-halves) -------------
// Swapped QK^T: S = mfma(K, Q, dt)  ->  lane holds S[key=g*4+r][qrow=col].
// PV A-fragments built in-register via ds_bpermute (no P LDS buffer).
__global__ __launch_bounds__(512) void attn_mfma(
    const u16* __restrict__ qh, const u16* __restrict__ kbf,
    const float* __restrict__ tep, const u16* __restrict__ vt,
    const float* __restrict__ bv, u16* __restrict__ obf) {
  const u32 orig = blockIdx.x;
  const u32 sw = (orig & 7) * 256 + (orig >> 3);   // XCD-bijective: 2 heads/XCD
  const int h = sw >> 7, bt = (sw >> 3) & 15, zc = sw & 7;
  const int b = bt >> 3, t = bt & 7;
  const int tid = threadIdx.x;
  const int lane = tid & 63, wv = tid >> 6;
  const int slot = wv & 3, half = wv >> 2;
  const int col = lane & 15, g = lane >> 4;

  __shared__ float cf[6400];   // 2 halves x 3 slots x 1024 acc + 192 lsum

  const int qrow0 = bt * 512 + zc * 64 + half * 32;
  s16x8 qa[2];
  #pragma unroll
  for (int m = 0; m < 2; ++m)
    qa[m] = *(const s16x8*)(qh + (size_t)(qrow0 + m * 16 + col) * 512 + h * 32 + g * 8);

  // dt[qrow=c] = q . tep_slot  (f32, folded into MFMA C-init)
  const float* tprow = tep + slot * 512 + h * 32;
  float t8[8];
  #pragma unroll
  for (int j = 0; j < 8; ++j) t8[j] = tprow[g * 8 + j];
  float dtc[2];
  #pragma unroll
  for (int m = 0; m < 2; ++m) {
    float p = 0.f;
    #pragma unroll
    for (int j = 0; j < 8; ++j) p = fmaf(bf2f((u16)qa[m][j]), t8[j], p);
    p += __shfl_xor(p, 16);
    p += __shfl_xor(p, 32);
    dtc[m] = p;
  }

  f32x4 acc[2][2] = {};
  float lsc[2] = {};

  const int fs = t + slot - 3;
  if (fs < 0) {
    // pad frame: 512 identical keys (tep only) with value bv
    const float bv0 = bv[h * 32 + col], bv1 = bv[h * 32 + 16 + col];
    #pragma unroll
    for (int m = 0; m < 2; ++m) {
      float e = __builtin_amdgcn_exp2f(dtc[m]) * 512.0f;
      if (g == 0) lsc[m] += e;
      #pragma unroll
      for (int r = 0; r < 4; ++r) {
        float egr = __int_as_float(
            __builtin_amdgcn_ds_bpermute((g * 4 + r) * 4, __float_as_int(e)));
        acc[m][0][r] += egr * bv0;
        acc[m][1][r] += egr * bv1;
      }
    }
  } else {
    const size_t krow0 = (size_t)((b * 8 + fs) * 512);
    const size_t vrow0 = (size_t)(((b * 8 + fs) * 16 + h) * 32);
    const int addrA = (col + 32 * (g & 1)) * 4;
    const int addrB = addrA + 64;
    const bool lowg = (g < 2);
    for (int it = 0; it < 8; ++it) {
      const int kk0 = it * 64;
      s16x8 kb[4], vf[2][2];
      #pragma unroll
      for (int n = 0; n < 4; ++n)
        kb[n] = *(const s16x8*)(kbf + (krow0 + kk0 + n * 16 + col) * 512 + h * 32 + g * 8);
      #pragma unroll
      for (int ks = 0; ks < 2; ++ks)
        #pragma unroll
        for (int nd = 0; nd < 2; ++nd)
          vf[ks][nd] = *(const s16x8*)(vt + (vrow0 + nd * 16 + col) * 512 + kk0 + ks * 32 + g * 8);
      #pragma unroll
      for (int m = 0; m < 2; ++m) {
        const f32x4 dti = {dtc[m], dtc[m], dtc[m], dtc[m]};
        u32 pr[4][2];
        float lacc = 0.f;
        #pragma unroll
        for (int n = 0; n < 4; ++n) {
          f32x4 S = __builtin_amdgcn_mfma_f32_16x16x32_bf16(kb[n], qa[m], dti, 0, 0, 0);
          f32x4 p;
          #pragma unroll
          for (int r = 0; r < 4; ++r) p[r] = __builtin_amdgcn_exp2f(S[r]);
          lacc += (p[0] + p[1]) + (p[2] + p[3]);
          pr[n][0] = cvtpk(p[0], p[1]);
          pr[n][1] = cvtpk(p[2], p[3]);
        }
        lsc[m] += lacc;
        #pragma unroll
        for (int ks = 0; ks < 2; ++ks) {
          union { u32 u[4]; s16x8 v; } pw;
          #pragma unroll
          for (int wq = 0; wq < 4; ++wq) {
            const int aA = (wq & 2) ? addrB : addrA;
            u32 va = (u32)__builtin_amdgcn_ds_bpermute(aA, (int)pr[2 * ks][wq & 1]);
            u32 vb = (u32)__builtin_amdgcn_ds_bpermute(aA, (int)pr[2 * ks + 1][wq & 1]);
            pw.u[wq] = lowg ? va : vb;
          }
          acc[m][0] = __builtin_amdgcn_mfma_f32_16x16x32_bf16(pw.v, vf[ks][0], acc[m][0], 0, 0, 0);
          acc[m][1] = __builtin_amdgcn_mfma_f32_16x16x32_bf16(pw.v, vf[ks][1], acc[m][1], 0, 0, 0);
        }
      }
    }
  }

  // reduce lsum over g-groups (per qrow=c)
  #pragma unroll
  for (int m = 0; m < 2; ++m) {
    lsc[m] += __shfl_xor(lsc[m], 16);
    lsc[m] += __shfl_xor(lsc[m], 32);
  }

  // additive cross-slot combine (valid: no-max softmax)
  if (slot > 0) {
    float* dst = cf + (size_t)(half * 3 + slot - 1) * 1024 + lane * 16;
    #pragma unroll
    for (int m = 0; m < 2; ++m) {
      *(f32x4*)(dst + m * 8) = acc[m][0];
      *(f32x4*)(dst + m * 8 + 4) = acc[m][1];
    }
    if (g == 0) {
      float* d2 = cf + 6144 + (half * 3 + slot - 1) * 32;
      #pragma unroll
      for (int m = 0; m < 2; ++m) d2[m * 16 + col] = lsc[m];
    }
  }
  __syncthreads();
  if (slot == 0) {
    #pragma unroll
    for (int s2 = 0; s2 < 3; ++s2) {
      const float* src = cf + (size_t)(half * 3 + s2) * 1024 + lane * 16;
      const float* l2 = cf + 6144 + (half * 3 + s2) * 32;
      #pragma unroll
      for (int m = 0; m < 2; ++m) {
        acc[m][0] += *(const f32x4*)(src + m * 8);
        acc[m][1] += *(const f32x4*)(src + m * 8 + 4);
        lsc[m] += l2[m * 16 + col];
      }
    }
    // normalize (lsum redistributed c -> (g,r)) + stage 32x32 bf16 tile
    u16* st = (u16*)(cf + half * 3 * 1024);
    #pragma unroll
    for (int m = 0; m < 2; ++m) {
      f32x4 inv;
      #pragma unroll
      for (int r = 0; r < 4; ++r) {
        float lr = __int_as_float(
            __builtin_amdgcn_ds_bpermute((g * 4 + r) * 4, __float_as_int(lsc[m])));
        inv[r] = 1.0f / lr;
      }
      #pragma unroll
      for (int nd = 0; nd < 2; ++nd)
        #pragma unroll
        for (int r = 0; r < 4; ++r)
          st[(m * 16 + g * 4 + r) * 32 + nd * 16 + col] = bf16b(acc[m][nd][r] * inv[r]);
    }
    asm volatile("s_waitcnt lgkmcnt(0)" ::: "memory");
    #pragma unroll
    for (int i = 0; i < 4; ++i) {
      const int row = i * 8 + (lane >> 3);
      u32x2 wq = *(u32x2*)&st[row * 32 + (lane & 7) * 4];
      *(u32x2*)(obf + (size_t)(qrow0 + row) * 512 + h * 32 + (lane & 7) * 4) = wq;
    }
  }
}

extern "C" void kernel_launch(void* const* d_in, const int* in_sizes, int n_in,
                              void* d_out, int out_size, void* d_ws, size_t ws_size,
                              hipStream_t stream) {
  (void)in_sizes; (void)n_in; (void)out_size; (void)ws_size;
  const float* hs    = (const float*)d_in[0];
  const float* w_in  = (const float*)d_in[1];
  const float* b_in  = (const float*)d_in[2];
  const float* w_out = (const float*)d_in[3];
  const float* b_out = (const float*)d_in[4];
  const float* te    = (const float*)d_in[5];

  u16* w16 = (u16*)d_ws;
  u16* hs_bf   = w16;                 // [0, 4194304)
  u16* win_bf  = w16 + 4194304;       // [4194304, 4980736)
  u16* wout_bf = w16 + 4980736;       // [4980736, 5242880)
  u16* qkv_bf  = w16 + 5242880;       // [5242880, 17825792)
  u16* qm_bf   = w16 + 17825792;      // [17825792, 22020096)
  u16* kc_bf   = w16 + 22020096;      // [22020096, 26214400)
  float* tep   = (float*)(w16 + 30408704);     // [30408704, 30412800)
  float2* tab  = (float2*)(w16 + 30412800);    // [30412800, 30445568)
  // gemm2 outputs: contiguous, NON-overlapping with qkv_bf (z=2 reads qkv live!)
  u16* qh_bf   = w16 + 30445568;      // [30445568, 34639872)
  u16* kbf     = w16 + 34639872;      // [34639872, 38834176)
  u16* vt      = w16 + 38834176;      // [38834176, 43028480)  (~86 MB total)
  u16* o_bf    = w16 + 22020096;      // over kc (consumed by gemm2)

  // 0) fused casts + trig table
  cast3_bf16<<<2560, 256, 0, stream>>>(hs, w_in, w_out, w16);
  ang_table_kernel<<<32, 256, 0, stream>>>(tab);

  // 1) qkv = hs @ Win^T + b_in  (bf16 out)
  gemm_bf16<<<dim3(12, 64), 256, 0, stream>>>(hs_bf, win_bf, b_in, qkv_bf, 1536, 512, 1.0f);

  // 2) RoPE + relayout (q,k only; v is an identity relayout read in-place by gemm2)
  rope_relayout_bf<<<4096, 256, 0, stream>>>(qkv_bf, tab, qm_bf, kc_bf);

  // 3) tep (exact f32 weights)
  tep_kernel<<<8, 256, 0, stream>>>(te, w_in + 512 * 512, b_in + 512, tep);

  // 4) batched second projections: qh(+bq,*SCL) | kbf(raw) | vt(transposed, +bv)
  gemm2_batched<<<dim3(4, 64, 3), 256, 0, stream>>>(qm_bf, qkv_bf, win_bf, b_in, qh_bf);

  // 5) attention (swapped-QK, bpermute PV, 8 waves/block)
  attn_mfma<<<2048, 512, 0, stream>>>(qh_bf, kbf, tep, vt, b_in + 1024, o_bf);

  // 6) out = o @ Wout^T + b_out (f32 out)
  gemm_f32out<<<dim3(4, 64), 256, 0, stream>>>(o_bf, wout_bf, b_out, (float*)d_out, 512, 512, 1.0f);
}

// Round 10
// 288.699 us; speedup vs baseline: 1.0093x; 1.0093x over previous
//
#include <hip/hip_runtime.h>

// B=2, T=8, H=16, W=16, E=512, n=16, d=32, S=4096, WINDOW=4
// frames BT=16, per-frame L2=512, keys/frame-window = 2048

#define LOG2T_OVER_16 0.83048202372184059f   // log2(10000)/16
#define SCL 0.25505837391169026f             // (1/sqrt(32)) * log2(e)

typedef unsigned short u16;
typedef unsigned int u32;
typedef __attribute__((ext_vector_type(2))) unsigned int u32x2;
typedef __attribute__((ext_vector_type(4))) float f32x4;
typedef __attribute__((ext_vector_type(8))) short s16x8;

__device__ __forceinline__ u16 bf16b(float x) {
  u32 u = __float_as_uint(x);
  u32 r = u + 0x7FFFu + ((u >> 16) & 1u);   // RNE
  return (u16)(r >> 16);
}
__device__ __forceinline__ float bf2f(u16 s) {
  return __uint_as_float(((u32)s) << 16);
}
__device__ __forceinline__ u32 cvtpk(float lo, float hi) {
  u32 r;
  asm("v_cvt_pk_bf16_f32 %0, %1, %2" : "=v"(r) : "v"(lo), "v"(hi));
  return r;
}

__device__ __forceinline__ void gld_lds16(const u16* g, u16* l) {
  __builtin_amdgcn_global_load_lds(
      (const __attribute__((address_space(1))) unsigned int*)g,
      (__attribute__((address_space(3))) unsigned int*)l, 16, 0, 0);
}

// ---------------- fused cast f32 -> bf16 of hs, w_in, w_out (contiguous dst) ----------------
__global__ __launch_bounds__(256) void cast3_bf16(
    const float* __restrict__ a, const float* __restrict__ b,
    const float* __restrict__ c, u16* __restrict__ dst) {
  const int i = blockIdx.x * 256 + threadIdx.x;
  const float* s;
  int so;
  if (i < 524288) { s = a; so = i; }
  else if (i < 622592) { s = b; so = i - 524288; }
  else { s = c; so = i - 622592; }
  float4 x = ((const float4*)s)[so * 2], y = ((const float4*)s)[so * 2 + 1];
  union { u32 u[4]; s16x8 v; } w;
  w.u[0] = cvtpk(x.x, x.y); w.u[1] = cvtpk(x.z, x.w);
  w.u[2] = cvtpk(y.x, y.y); w.u[3] = cvtpk(y.z, y.w);
  ((s16x8*)dst)[i] = w.v;
}

// ---------------- MFMA GEMM core ----------------
// MODE 0: bf16 C row-major. MODE 1: f32 C row-major. MODE 2: bf16 written
// transposed into vt[((frame*16+h)*32+dd)*512 + key] (frame=row>>9, key=row&511).
template<int MODE>
__device__ __forceinline__ void gemm_core(
    const u16* __restrict__ A, const u16* __restrict__ Bw,
    const float* __restrict__ bias, void* __restrict__ Cp,
    int N, int K, int lda, float scale, u16* As, u16* Bs) {
  const int tid = threadIdx.x;
  const int row0 = blockIdx.y * 128;
  const int col0 = blockIdx.x * 128;
  const int lane = tid & 63, wid = tid >> 6;
  const int col = lane & 15, g = lane >> 4;
  const int wm = wid >> 1, wn = wid & 1;

  const int s0 = tid, s1 = 256 + tid;
  const int r0 = s0 >> 2, kp0 = (s0 & 3) * 8;
  const int r1 = s1 >> 2, kp1 = (s1 & 3) * 8;

  f32x4 acc[4][4] = {};

  auto stage = [&](int buf, int k0) {
    u16* ab = As + buf * 4096;
    u16* bb = Bs + buf * 4096;
    gld_lds16(A + (size_t)(row0 + r0) * lda + k0 + kp0, ab + s0 * 8);
    gld_lds16(A + (size_t)(row0 + r1) * lda + k0 + kp1, ab + s1 * 8);
    gld_lds16(Bw + (size_t)(col0 + r0) * K + k0 + kp0, bb + s0 * 8);
    gld_lds16(Bw + (size_t)(col0 + r1) * K + k0 + kp1, bb + s1 * 8);
  };

  stage(0, 0);
  asm volatile("s_waitcnt vmcnt(0)" ::: "memory");
  __syncthreads();

  const int NT = K / 32;
  int cur = 0;
  for (int t = 0; t < NT; ++t) {
    if (t + 1 < NT) stage(cur ^ 1, (t + 1) * 32);
    const u16* ab = As + cur * 4096;
    const u16* bb = Bs + cur * 4096;
    s16x8 a[4], b[4];
    #pragma unroll
    for (int i = 0; i < 4; ++i)
      a[i] = *(const s16x8*)(ab + (wm * 64 + i * 16 + col) * 32 + g * 8);
    #pragma unroll
    for (int i = 0; i < 4; ++i)
      b[i] = *(const s16x8*)(bb + (wn * 64 + i * 16 + col) * 32 + g * 8);
    #pragma unroll
    for (int mi = 0; mi < 4; ++mi)
      #pragma unroll
      for (int ni = 0; ni < 4; ++ni)
        acc[mi][ni] = __builtin_amdgcn_mfma_f32_16x16x32_bf16(a[mi], b[ni], acc[mi][ni], 0, 0, 0);
    asm volatile("s_waitcnt vmcnt(0)" ::: "memory");
    __syncthreads();
    cur ^= 1;
  }

  const int crow = row0 + wm * 64, ccol = col0 + wn * 64;
  #pragma unroll
  for (int mi = 0; mi < 4; ++mi) {
    #pragma unroll
    for (int ni = 0; ni < 4; ++ni) {
      const int cc = ccol + ni * 16 + col;
      const float bb_ = bias ? bias[cc] : 0.0f;
      if (MODE == 2) {
        const int key0 = crow + mi * 16 + g * 4;   // 4 consecutive keys
        u16* dst = (u16*)Cp +
            ((size_t)((key0 >> 9) * 16 + (cc >> 5)) * 32 + (cc & 31)) * 512 + (key0 & 511);
        union { u16 s[4]; u32x2 v; } pk;
        #pragma unroll
        for (int r = 0; r < 4; ++r) pk.s[r] = bf16b(acc[mi][ni][r] + bb_);
        *(u32x2*)dst = pk.v;
      } else {
        #pragma unroll
        for (int r = 0; r < 4; ++r) {
          const int rr = crow + mi * 16 + g * 4 + r;
          float v = (acc[mi][ni][r] + bb_) * scale;
          if (MODE == 1) ((float*)Cp)[(size_t)rr * N + cc] = v;
          else           ((u16*)Cp)[(size_t)rr * N + cc] = bf16b(v);
        }
      }
    }
  }
}

__global__ __launch_bounds__(256) void gemm_bf16(
    const u16* __restrict__ A, const u16* __restrict__ Bw,
    const float* __restrict__ bias, u16* __restrict__ C, int N, int K, float scale) {
  __shared__ u16 As[2 * 4096];
  __shared__ u16 Bs[2 * 4096];
  gemm_core<0>(A, Bw, bias, C, N, K, K, scale, As, Bs);
}

__global__ __launch_bounds__(256) void gemm_f32out(
    const u16* __restrict__ A, const u16* __restrict__ Bw,
    const float* __restrict__ bias, float* __restrict__ C, int N, int K, float scale) {
  __shared__ u16 As[2 * 4096];
  __shared__ u16 Bs[2 * 4096];
  gemm_core<1>(A, Bw, bias, C, N, K, K, scale, As, Bs);
}

// batched second projection: z=0 qh(+bq,*SCL) | z=1 kbf(raw) | z=2 V: reads qkv
// strided (lda=1536), writes vt transposed (+bv). Cb must NOT alias qkv.
__global__ __launch_bounds__(256) void gemm2_batched(
    const u16* __restrict__ Ab, const u16* __restrict__ qkv,
    const u16* __restrict__ Wb, const float* __restrict__ b_in,
    u16* __restrict__ Cb) {
  __shared__ u16 As[2 * 4096];
  __shared__ u16 Bs[2 * 4096];
  const int z = blockIdx.z;
  const u16* Bw = Wb + (size_t)z * 262144;
  u16* C = Cb + (size_t)z * 4194304;
  if (z == 2) {
    gemm_core<2>(qkv + 1024, Bw, b_in + 1024, C, 512, 512, 1536, 1.0f, As, Bs);
  } else {
    const float* bias = (z == 0) ? b_in : nullptr;
    const float scale = (z == 0) ? SCL : 1.0f;
    gemm_core<0>(Ab + (size_t)z * 4194304, Bw, bias, C, 512, 512, 512, scale, As, Bs);
  }
}

// ------------- angle table: tab[j][u] = {cos, sin} (512 x 16) -------------
__global__ __launch_bounds__(256) void ang_table_kernel(float2* __restrict__ tab) {
  const int idx = blockIdx.x * 256 + threadIdx.x;  // 0..8191
  const int j = idx >> 4, u = idx & 15;
  float ang;
  if (j < 256) {
    ang = (float)j * exp2f(-(float)u * LOG2T_OVER_16);
  } else {
    const int jj = j - 256, hh = jj >> 4, ww = jj & 15;
    ang = (u < 8) ? (float)hh * exp2f(-(float)(2 * u) * LOG2T_OVER_16)
                  : (float)ww * exp2f(-(float)(2 * (u - 8) + 1) * LOG2T_OVER_16);
  }
  float s, c;
  sincosf(ang, &s, &c);
  tab[idx] = make_float2(c, s);
}

// ------------- RoPE + relayout (bf16): qkv(8192x1536) -> qm/kc (8192x512) -------------
__global__ __launch_bounds__(256) void rope_relayout_bf(
    const u16* __restrict__ qkv, const float2* __restrict__ tab,
    u16* __restrict__ qm, u16* __restrict__ kc) {
  const int R = blockIdx.x * 2 + (threadIdx.x >> 7);   // row 0..8191
  const int t2 = threadIdx.x & 127;
  const int j = R & 511, bt = R >> 9;
  const int b = bt >> 3, tt = bt & 7;
  const int head = t2 >> 3, u0 = (t2 & 7) * 2;
  const int e0 = head * 32 + u0 * 2;

  const int tok = (j < 256) ? (b * 4096 + tt * 256 + j)
                            : (b * 4096 + 2048 + tt * 256 + (j - 256));
  float4 cs = *(const float4*)&tab[j * 16 + u0];
  const float c0 = cs.x, s0 = cs.y, c1 = cs.z, s1 = cs.w;

  const size_t base = (size_t)tok * 1536 + e0;
  const size_t orow = (size_t)R * 512 + e0;

  auto rot = [&](u32x2 in) -> u32x2 {
    float r0 = bf2f((u16)(in[0] & 0xffff)), i0 = bf2f((u16)(in[0] >> 16));
    float r1 = bf2f((u16)(in[1] & 0xffff)), i1 = bf2f((u16)(in[1] >> 16));
    u32x2 o;
    o[0] = cvtpk(r0 * c0 - i0 * s0, r0 * s0 + i0 * c0);
    o[1] = cvtpk(r1 * c1 - i1 * s1, r1 * s1 + i1 * c1);
    return o;
  };
  *(u32x2*)(qm + orow) = rot(*(const u32x2*)(qkv + base));
  *(u32x2*)(kc + orow) = rot(*(const u32x2*)(qkv + base + 512));
}

// ------------- tep[i][c] = te[i] @ Wk[c,:] + bk[c]  (4 x 512, exact f32) -------------
__global__ __launch_bounds__(256) void tep_kernel(
    const float* __restrict__ te, const float* __restrict__ Wk,
    const float* __restrict__ bk, float* __restrict__ tep) {
  const int idx = blockIdx.x * 256 + threadIdx.x;
  const int i = idx >> 9, c = idx & 511;
  float s = bk[c];
  const float* terow = te + i * 512;
  const float* wrow = Wk + (size_t)c * 512;
  #pragma unroll 8
  for (int e = 0; e < 512; ++e) s = fmaf(terow[e], wrow[e], s);
  tep[idx] = s;
}

// ------------- MFMA flash attention: 8 waves/block = (4 slots) x (2 row-halves) -------------
// Swapped QK^T: S = mfma(K, Q, dt)  ->  lane holds S[key=g*4+r][qrow=col].
// PV A-fragments built in-register via v_permlane{32,16}_swap (VALU-only, no LDS).
__global__ __launch_bounds__(512) void attn_mfma(
    const u16* __restrict__ qh, const u16* __restrict__ kbf,
    const float* __restrict__ tep, const u16* __restrict__ vt,
    const float* __restrict__ bv, u16* __restrict__ obf) {
  const u32 orig = blockIdx.x;
  const u32 sw = (orig & 7) * 256 + (orig >> 3);   // XCD-bijective: 2 heads/XCD
  const int h = sw >> 7, bt = (sw >> 3) & 15, zc = sw & 7;
  const int b = bt >> 3, t = bt & 7;
  const int tid = threadIdx.x;
  const int lane = tid & 63, wv = tid >> 6;
  const int slot = wv & 3, half = wv >> 2;
  const int col = lane & 15, g = lane >> 4;

  __shared__ float cf[6400];   // 2 halves x 3 slots x 1024 acc + 192 lsum

  const int qrow0 = bt * 512 + zc * 64 + half * 32;
  s16x8 qa[2];
  #pragma unroll
  for (int m = 0; m < 2; ++m)
    qa[m] = *(const s16x8*)(qh + (size_t)(qrow0 + m * 16 + col) * 512 + h * 32 + g * 8);

  // dt[qrow=c] = q . tep_slot  (f32, folded into MFMA C-init)
  const float* tprow = tep + slot * 512 + h * 32;
  float t8[8];
  #pragma unroll
  for (int j = 0; j < 8; ++j) t8[j] = tprow[g * 8 + j];
  float dtc[2];
  #pragma unroll
  for (int m = 0; m < 2; ++m) {
    float p = 0.f;
    #pragma unroll
    for (int j = 0; j < 8; ++j) p = fmaf(bf2f((u16)qa[m][j]), t8[j], p);
    p += __shfl_xor(p, 16);
    p += __shfl_xor(p, 32);
    dtc[m] = p;
  }

  f32x4 acc[2][2] = {};
  float lsc[2] = {};

  const int fs = t + slot - 3;
  if (fs < 0) {
    // pad frame: 512 identical keys (tep only) with value bv
    const float bv0 = bv[h * 32 + col], bv1 = bv[h * 32 + 16 + col];
    #pragma unroll
    for (int m = 0; m < 2; ++m) {
      float e = __builtin_amdgcn_exp2f(dtc[m]) * 512.0f;
      if (g == 0) lsc[m] += e;
      #pragma unroll
      for (int r = 0; r < 4; ++r) {
        float egr = __int_as_float(
            __builtin_amdgcn_ds_bpermute((g * 4 + r) * 4, __float_as_int(e)));
        acc[m][0][r] += egr * bv0;
        acc[m][1][r] += egr * bv1;
      }
    }
  } else {
    const size_t krow0 = (size_t)((b * 8 + fs) * 512);
    const size_t vrow0 = (size_t)(((b * 8 + fs) * 16 + h) * 32);
    for (int it = 0; it < 8; ++it) {
      const int kk0 = it * 64;
      s16x8 kb[4], vf[2][2];
      #pragma unroll
      for (int n = 0; n < 4; ++n)
        kb[n] = *(const s16x8*)(kbf + (krow0 + kk0 + n * 16 + col) * 512 + h * 32 + g * 8);
      #pragma unroll
      for (int ks = 0; ks < 2; ++ks)
        #pragma unroll
        for (int nd = 0; nd < 2; ++nd)
          vf[ks][nd] = *(const s16x8*)(vt + (vrow0 + nd * 16 + col) * 512 + kk0 + ks * 32 + g * 8);
      #pragma unroll
      for (int m = 0; m < 2; ++m) {
        const f32x4 dti = {dtc[m], dtc[m], dtc[m], dtc[m]};
        u32 pr[4][2];
        float lacc = 0.f;
        #pragma unroll
        for (int n = 0; n < 4; ++n) {
          f32x4 S = __builtin_amdgcn_mfma_f32_16x16x32_bf16(kb[n], qa[m], dti, 0, 0, 0);
          f32x4 p;
          #pragma unroll
          for (int r = 0; r < 4; ++r) p[r] = __builtin_amdgcn_exp2f(S[r]);
          lacc += (p[0] + p[1]) + (p[2] + p[3]);
          pr[n][0] = cvtpk(p[0], p[1]);
          pr[n][1] = cvtpk(p[2], p[3]);
        }
        lsc[m] += lacc;
        // Build PV A-fragments in-register: per ks, combine tiles n=2ks (X) and
        // n=2ks+1 (Y). P32(X,Y)->(U=[X.lo|Y.lo], V=[X.hi|Y.hi]); P16(U,V)->
        // (W0=[X@self,X@+16,Y@-32,Y@-16], W2=[X@+16.., ..]). Verified per-quadrant.
        #pragma unroll
        for (int ks = 0; ks < 2; ++ks) {
          u32 a0 = pr[2 * ks][0],     a1 = pr[2 * ks][1];
          u32 b0 = pr[2 * ks + 1][0], b1 = pr[2 * ks + 1][1];
          asm("v_permlane32_swap_b32 %0, %1" : "+v"(a0), "+v"(b0));
          asm("v_permlane16_swap_b32 %0, %1" : "+v"(a0), "+v"(b0));
          asm("v_permlane32_swap_b32 %0, %1" : "+v"(a1), "+v"(b1));
          asm("v_permlane16_swap_b32 %0, %1" : "+v"(a1), "+v"(b1));
          union { u32 u[4]; s16x8 v; } pw;
          pw.u[0] = a0; pw.u[1] = a1; pw.u[2] = b0; pw.u[3] = b1;
          acc[m][0] = __builtin_amdgcn_mfma_f32_16x16x32_bf16(pw.v, vf[ks][0], acc[m][0], 0, 0, 0);
          acc[m][1] = __builtin_amdgcn_mfma_f32_16x16x32_bf16(pw.v, vf[ks][1], acc[m][1], 0, 0, 0);
        }
      }
    }
  }

  // reduce lsum over g-groups (per qrow=c)
  #pragma unroll
  for (int m = 0; m < 2; ++m) {
    lsc[m] += __shfl_xor(lsc[m], 16);
    lsc[m] += __shfl_xor(lsc[m], 32);
  }

  // additive cross-slot combine (valid: no-max softmax)
  if (slot > 0) {
    float* dst = cf + (size_t)(half * 3 + slot - 1) * 1024 + lane * 16;
    #pragma unroll
    for (int m = 0; m < 2; ++m) {
      *(f32x4*)(dst + m * 8) = acc[m][0];
      *(f32x4*)(dst + m * 8 + 4) = acc[m][1];
    }
    if (g == 0) {
      float* d2 = cf + 6144 + (half * 3 + slot - 1) * 32;
      #pragma unroll
      for (int m = 0; m < 2; ++m) d2[m * 16 + col] = lsc[m];
    }
  }
  __syncthreads();
  if (slot == 0) {
    #pragma unroll
    for (int s2 = 0; s2 < 3; ++s2) {
      const float* src = cf + (size_t)(half * 3 + s2) * 1024 + lane * 16;
      const float* l2 = cf + 6144 + (half * 3 + s2) * 32;
      #pragma unroll
      for (int m = 0; m < 2; ++m) {
        acc[m][0] += *(const f32x4*)(src + m * 8);
        acc[m][1] += *(const f32x4*)(src + m * 8 + 4);
        lsc[m] += l2[m * 16 + col];
      }
    }
    // normalize (lsum redistributed c -> (g,r)) + stage 32x32 bf16 tile
    u16* st = (u16*)(cf + half * 3 * 1024);
    #pragma unroll
    for (int m = 0; m < 2; ++m) {
      f32x4 inv;
      #pragma unroll
      for (int r = 0; r < 4; ++r) {
        float lr = __int_as_float(
            __builtin_amdgcn_ds_bpermute((g * 4 + r) * 4, __float_as_int(lsc[m])));
        inv[r] = 1.0f / lr;
      }
      #pragma unroll
      for (int nd = 0; nd < 2; ++nd)
        #pragma unroll
        for (int r = 0; r < 4; ++r)
          st[(m * 16 + g * 4 + r) * 32 + nd * 16 + col] = bf16b(acc[m][nd][r] * inv[r]);
    }
    asm volatile("s_waitcnt lgkmcnt(0)" ::: "memory");
    #pragma unroll
    for (int i = 0; i < 4; ++i) {
      const int row = i * 8 + (lane >> 3);
      u32x2 wq = *(u32x2*)&st[row * 32 + (lane & 7) * 4];
      *(u32x2*)(obf + (size_t)(qrow0 + row) * 512 + h * 32 + (lane & 7) * 4) = wq;
    }
  }
}

extern "C" void kernel_launch(void* const* d_in, const int* in_sizes, int n_in,
                              void* d_out, int out_size, void* d_ws, size_t ws_size,
                              hipStream_t stream) {
  (void)in_sizes; (void)n_in; (void)out_size; (void)ws_size;
  const float* hs    = (const float*)d_in[0];
  const float* w_in  = (const float*)d_in[1];
  const float* b_in  = (const float*)d_in[2];
  const float* w_out = (const float*)d_in[3];
  const float* b_out = (const float*)d_in[4];
  const float* te    = (const float*)d_in[5];

  u16* w16 = (u16*)d_ws;
  u16* hs_bf   = w16;                 // [0, 4194304)
  u16* win_bf  = w16 + 4194304;       // [4194304, 4980736)
  u16* wout_bf = w16 + 4980736;       // [4980736, 5242880)
  u16* qkv_bf  = w16 + 5242880;       // [5242880, 17825792)
  u16* qm_bf   = w16 + 17825792;      // [17825792, 22020096)
  u16* kc_bf   = w16 + 22020096;      // [22020096, 26214400)
  float* tep   = (float*)(w16 + 30408704);     // [30408704, 30412800)
  float2* tab  = (float2*)(w16 + 30412800);    // [30412800, 30445568)
  // gemm2 outputs: contiguous, NON-overlapping with qkv_bf (z=2 reads qkv live!)
  u16* qh_bf   = w16 + 30445568;      // [30445568, 34639872)
  u16* kbf     = w16 + 34639872;      // [34639872, 38834176)
  u16* vt      = w16 + 38834176;      // [38834176, 43028480)  (~86 MB total)
  u16* o_bf    = w16 + 22020096;      // over kc (consumed by gemm2)

  // 0) fused casts + trig table
  cast3_bf16<<<2560, 256, 0, stream>>>(hs, w_in, w_out, w16);
  ang_table_kernel<<<32, 256, 0, stream>>>(tab);

  // 1) qkv = hs @ Win^T + b_in  (bf16 out)
  gemm_bf16<<<dim3(12, 64), 256, 0, stream>>>(hs_bf, win_bf, b_in, qkv_bf, 1536, 512, 1.0f);

  // 2) RoPE + relayout (q,k only; v is an identity relayout read in-place by gemm2)
  rope_relayout_bf<<<4096, 256, 0, stream>>>(qkv_bf, tab, qm_bf, kc_bf);

  // 3) tep (exact f32 weights)
  tep_kernel<<<8, 256, 0, stream>>>(te, w_in + 512 * 512, b_in + 512, tep);

  // 4) batched second projections: qh(+bq,*SCL) | kbf(raw) | vt(transposed, +bv)
  gemm2_batched<<<dim3(4, 64, 3), 256, 0, stream>>>(qm_bf, qkv_bf, win_bf, b_in, qh_bf);

  // 5) attention (swapped-QK, permlane PV, 8 waves/block)
  attn_mfma<<<2048, 512, 0, stream>>>(qh_bf, kbf, tep, vt, b_in + 1024, o_bf);

  // 6) out = o @ Wout^T + b_out (f32 out)
  gemm_f32out<<<dim3(4, 64), 256, 0, stream>>>(o_bf, wout_bf, b_out, (float*)d_out, 512, 512, 1.0f);
}